// Round 8
// baseline (195.922 us; speedup 1.0000x reference)
//
#include <hip/hip_runtime.h>
#include <hip/hip_bf16.h>

typedef __attribute__((ext_vector_type(8))) short short8;
typedef __attribute__((ext_vector_type(4))) short short4v;
typedef __attribute__((ext_vector_type(4))) float floatx4;
typedef unsigned int u32;

#define BB 8
#define CC 256
#define ICH 128
#define TT 4096
#define SS 2048
static constexpr float BN_EPS = 1e-5f;
static constexpr float INV_S  = 1.0f / 2048.0f;
static constexpr float INV_BT = 1.0f / 32768.0f;   // 1/(B*T)

// async global->LDS DMA, 16 B per lane; LDS dest = wave-uniform base + lane*16
typedef const __attribute__((address_space(1))) u32* gas_ptr;
typedef __attribute__((address_space(3))) u32* las_ptr;
__device__ __forceinline__ void gl_lds16(const void* g, void* l) {
    __builtin_amdgcn_global_load_lds((gas_ptr)g, (las_ptr)l, 16, 0, 0);
}

// ---------------------------------------------------------------------------
// k0x: transpose + convert  x[b][c][t] (f32) -> xt[b][t][c] (bf16).
// z==8 slice (y==0) additionally converts phi_w|g_w -> bf16 Wf (fused k0w).
// grid (64 t-tiles, 4 c-tiles, 9), block 256
// ---------------------------------------------------------------------------
__global__ __launch_bounds__(256) void k0x_transpose(
    const float* __restrict__ x, __hip_bfloat16* __restrict__ xt,
    const float* __restrict__ phi_w, const float* __restrict__ g_w,
    __hip_bfloat16* __restrict__ Wf)
{
    if (blockIdx.z == 8) {                      // fused weight conversion
        if (blockIdx.y != 0) return;
        int idx = blockIdx.x * 256 + threadIdx.x;   // 0..16383, 4 floats each
        const float* src = (idx < 8192) ? (phi_w + (size_t)idx * 4)
                                        : (g_w + (size_t)(idx - 8192) * 4);
        float4 v = *(const float4*)src;
        alignas(8) __hip_bfloat16 t[4];
        t[0] = __float2bfloat16(v.x); t[1] = __float2bfloat16(v.y);
        t[2] = __float2bfloat16(v.z); t[3] = __float2bfloat16(v.w);
        *(short4v*)(Wf + (size_t)idx * 4) = *(const short4v*)t;
        return;
    }

    __shared__ float Tl[64][65];
    const int b = blockIdx.z, cb = blockIdx.y * 64, tb = blockIdx.x * 64;
    const int tid = threadIdx.x;
    #pragma unroll
    for (int it = 0; it < 4; ++it) {
        int idx = tid + 256 * it;
        int row = idx >> 4, c4 = idx & 15;
        float4 v = *(const float4*)(x + ((size_t)b * CC + cb + row) * TT + tb + c4 * 4);
        Tl[row][c4 * 4 + 0] = v.x; Tl[row][c4 * 4 + 1] = v.y;
        Tl[row][c4 * 4 + 2] = v.z; Tl[row][c4 * 4 + 3] = v.w;
    }
    __syncthreads();
    #pragma unroll
    for (int it = 0; it < 2; ++it) {
        int idx = tid + 256 * it;
        int trow = idx >> 3, ch = idx & 7;
        alignas(16) __hip_bfloat16 tmp[8];
        #pragma unroll
        for (int e = 0; e < 8; ++e) tmp[e] = __float2bfloat16(Tl[ch * 8 + e][trow]);
        *(short8*)(xt + ((size_t)b * TT + tb + trow) * CC + cb + ch * 8) = *(const short8*)tmp;
    }
}

// ---------------------------------------------------------------------------
// k1: m97-style MFMA conv1x1 (stacked phi|g) + maxpool2 epilogue.
// grid (32 pre-pool t-tiles of 128, 2 m-tiles, 8 b), block 256 (4 waves)
// ---------------------------------------------------------------------------
__global__ __launch_bounds__(256) void k1_mfma(
    const __hip_bfloat16* __restrict__ Wf, const float* __restrict__ phi_b,
    const float* __restrict__ g_b, const __hip_bfloat16* __restrict__ xt,
    __hip_bfloat16* __restrict__ phi_g)
{
    __shared__ short lds[128 * 132];      // staging (32 KB) / Out (33 KB), reused
    short* As = lds;
    short* Bs = lds + 128 * 64;

    const int b  = blockIdx.z;
    const int m0 = blockIdx.y * 128;
    const int tb = blockIdx.x * 128;      // pre-pool t base
    const int s0 = blockIdx.x * 64;       // pooled output base
    const int tid = threadIdx.x;
    const int w = tid >> 6, l = tid & 63;
    const int quad = l >> 4, lm = l & 15;
    const int wm = (w & 1) * 64, wn = (w >> 1) * 64;
    const int rs = l >> 3, cs = (l & 7) * 8;   // staging row-sub / col

    const __hip_bfloat16* Ap = Wf + (size_t)m0 * CC;
    const __hip_bfloat16* Bp = xt + ((size_t)b * TT + tb) * CC;

    floatx4 acc[4][4];
    #pragma unroll
    for (int i = 0; i < 4; ++i)
        #pragma unroll
        for (int j = 0; j < 4; ++j) acc[i][j] = (floatx4)0.f;

    for (int kc = 0; kc < 4; ++kc) {
        const int k0 = kc * 64;
        const int rbase = w * 32;
        #pragma unroll
        for (int t = 0; t < 4; ++t) {
            gl_lds16(Ap + (size_t)(rbase + t * 8 + rs) * CC + k0 + cs, &As[(rbase + t * 8) * 64]);
            gl_lds16(Bp + (size_t)(rbase + t * 8 + rs) * CC + k0 + cs, &Bs[(rbase + t * 8) * 64]);
        }
        __syncthreads();
        #pragma unroll
        for (int ks = 0; ks < 2; ++ks) {
            short8 a[4], bb[4];
            #pragma unroll
            for (int i = 0; i < 4; ++i)
                a[i] = *(const short8*)&As[(wm + i * 16 + lm) * 64 + ks * 32 + quad * 8];
            #pragma unroll
            for (int j = 0; j < 4; ++j)
                bb[j] = *(const short8*)&Bs[(wn + j * 16 + lm) * 64 + ks * 32 + quad * 8];
            #pragma unroll
            for (int i = 0; i < 4; ++i)
                #pragma unroll
                for (int j = 0; j < 4; ++j)
                    acc[i][j] = __builtin_amdgcn_mfma_f32_16x16x32_bf16(a[i], bb[j], acc[i][j], 0, 0, 0);
        }
        __syncthreads();
    }

    // epilogue: stage pre-pool bf16 tile (stride 132), then pool + bias, wide stores
    __hip_bfloat16* Out = (__hip_bfloat16*)lds;
    #pragma unroll
    for (int i = 0; i < 4; ++i)
        #pragma unroll
        for (int j = 0; j < 4; ++j)
            #pragma unroll
            for (int r = 0; r < 4; ++r)
                Out[(wm + i * 16 + quad * 4 + r) * 132 + wn + j * 16 + lm] =
                    __float2bfloat16(acc[i][j][r]);
    __syncthreads();
    #pragma unroll
    for (int it = 0; it < 4; ++it) {
        int idx = tid + 256 * it;
        int orow = idx >> 3, grp = idx & 7;
        int o = m0 + orow;
        float bias = (o < ICH) ? phi_b[o] : g_b[o - ICH];
        short8 v0 = *(const short8*)&Out[orow * 132 + grp * 16];
        short8 v1 = *(const short8*)&Out[orow * 132 + grp * 16 + 8];
        const __hip_bfloat16* p0 = (const __hip_bfloat16*)&v0;
        const __hip_bfloat16* p1 = (const __hip_bfloat16*)&v1;
        alignas(16) __hip_bfloat16 o8[8];
        #pragma unroll
        for (int e = 0; e < 4; ++e)
            o8[e] = __float2bfloat16(
                fmaxf(__bfloat162float(p0[2 * e]), __bfloat162float(p0[2 * e + 1])) + bias);
        #pragma unroll
        for (int e = 0; e < 4; ++e)
            o8[4 + e] = __float2bfloat16(
                fmaxf(__bfloat162float(p1[2 * e]), __bfloat162float(p1[2 * e + 1])) + bias);
        *(short8*)(phi_g + ((size_t)b * CC + o) * SS + s0 + grp * 8) = *(const short8*)o8;
    }
}

// ---------------------------------------------------------------------------
// k2: MFMA Gram partials  Mpart[b][sc][c'][c] = sum_{s in 128-chunk sc}
// grid (16 sc, 8 b), block 256, K-loop of 2 BK=64 tiles
// ---------------------------------------------------------------------------
__global__ __launch_bounds__(256) void k2_mfma(
    const __hip_bfloat16* __restrict__ phi_g, float* __restrict__ Mpart)
{
    __shared__ short lds[2 * 128 * 64];
    short* As = lds;
    short* Bs = lds + 128 * 64;
    const int sc = blockIdx.x, b = blockIdx.y;
    const int tid = threadIdx.x;
    const int w = tid >> 6, l = tid & 63;
    const int quad = l >> 4, lm = l & 15;
    const int wm = (w & 1) * 64, wn = (w >> 1) * 64;
    const int rs = l >> 3, cs = (l & 7) * 8;

    const __hip_bfloat16* Ap = phi_g + (size_t)b * CC * SS + sc * 128;   // phi rows
    const __hip_bfloat16* Bp = Ap + (size_t)ICH * SS;                     // g rows

    floatx4 acc[4][4];
    #pragma unroll
    for (int i = 0; i < 4; ++i)
        #pragma unroll
        for (int j = 0; j < 4; ++j) acc[i][j] = (floatx4)0.f;

    for (int kc = 0; kc < 2; ++kc) {
        const int k0 = kc * 64;
        const int rbase = w * 32;
        #pragma unroll
        for (int t = 0; t < 4; ++t) {
            gl_lds16(Ap + (size_t)(rbase + t * 8 + rs) * SS + k0 + cs, &As[(rbase + t * 8) * 64]);
            gl_lds16(Bp + (size_t)(rbase + t * 8 + rs) * SS + k0 + cs, &Bs[(rbase + t * 8) * 64]);
        }
        __syncthreads();
        #pragma unroll
        for (int ks = 0; ks < 2; ++ks) {
            short8 a[4], bb[4];
            #pragma unroll
            for (int i = 0; i < 4; ++i)
                a[i] = *(const short8*)&As[(wm + i * 16 + lm) * 64 + ks * 32 + quad * 8];
            #pragma unroll
            for (int j = 0; j < 4; ++j)
                bb[j] = *(const short8*)&Bs[(wn + j * 16 + lm) * 64 + ks * 32 + quad * 8];
            #pragma unroll
            for (int i = 0; i < 4; ++i)
                #pragma unroll
                for (int j = 0; j < 4; ++j)
                    acc[i][j] = __builtin_amdgcn_mfma_f32_16x16x32_bf16(a[i], bb[j], acc[i][j], 0, 0, 0);
        }
        __syncthreads();
    }

    float* dst = Mpart + ((size_t)(b * 16 + sc)) * ICH * ICH;
    #pragma unroll
    for (int i = 0; i < 4; ++i)
        #pragma unroll
        for (int j = 0; j < 4; ++j)
            #pragma unroll
            for (int r = 0; r < 4; ++r)
                dst[(size_t)(wm + i * 16 + quad * 4 + r) * ICH + wn + j * 16 + lm] = acc[i][j][r];
}

// ---------------------------------------------------------------------------
// k2b: reduce 16 partials -> Msum[b][128][128]
// ---------------------------------------------------------------------------
__global__ __launch_bounds__(256) void k2b_reduce(
    const float* __restrict__ Mpart, float* __restrict__ Msum)
{
    const int b = blockIdx.y;
    const size_t f4 = (size_t)blockIdx.x * 256 + threadIdx.x;   // 0..4095 per b
    const float* src = Mpart + (size_t)b * 16 * 16384 + f4 * 4;
    float4 s = {0.f, 0.f, 0.f, 0.f};
    #pragma unroll
    for (int sc = 0; sc < 16; ++sc) {
        float4 v = *(const float4*)(src + (size_t)sc * 16384);
        s.x += v.x; s.y += v.y; s.z += v.z; s.w += v.w;
    }
    *(float4*)(Msum + (size_t)b * 16384 + f4 * 4) = s;
}

// ---------------------------------------------------------------------------
// k3_fused: per (cob 64-row tile, b):
//   phase A: KbL[co][c'] = (1/S) sum_c w_w[co][c] * Msum[b][c'][c]   (in LDS)
//   q[b][co] = w_b[co] + KbL[co] . theta_b
//   phase B: P[b][co][ci] = sum_c' KbL[co][c'] * theta_w[c'][ci]  (bf16 out)
// grid (4 cob, 8 b), block 256. Replaces k3a + k3b + k3c.
// ---------------------------------------------------------------------------
__global__ __launch_bounds__(256) void k3_fused(
    const float* __restrict__ w_w, const float* __restrict__ Msum,
    const float* __restrict__ theta_w, const float* __restrict__ theta_b,
    const float* __restrict__ w_b, __hip_bfloat16* __restrict__ P,
    float* __restrict__ q)
{
    __shared__ float S1[64 * 133];   // Bl [c][c'(128)] -> KbL [co][c'] (stride 133)
    __shared__ float S2[64 * 65];    // Al [c][co]      -> theta chunk [c'][ci]
    const int b = blockIdx.y;
    const int cob = blockIdx.x * 64;
    const int tid = threadIdx.x;
    const int tx = tid & 15, ty = tid >> 4;

    // ---- phase A: Kb tile ----
    float acc[4][8];
    #pragma unroll
    for (int i = 0; i < 4; ++i)
        #pragma unroll
        for (int j = 0; j < 8; ++j) acc[i][j] = 0.f;

    for (int kc2 = 0; kc2 < 2; ++kc2) {
        #pragma unroll
        for (int r = 0; r < 4; ++r) {                 // w_w -> S2 [c][co]
            int idx = tid + 256 * r;
            int row = idx >> 4, c4 = idx & 15;        // row = co
            float4 v = *(const float4*)(w_w + (size_t)(cob + row) * ICH + kc2 * 64 + c4 * 4);
            S2[(c4 * 4 + 0) * 65 + row] = v.x; S2[(c4 * 4 + 1) * 65 + row] = v.y;
            S2[(c4 * 4 + 2) * 65 + row] = v.z; S2[(c4 * 4 + 3) * 65 + row] = v.w;
        }
        #pragma unroll
        for (int r = 0; r < 8; ++r) {                 // Msum -> S1 [c][c']
            int idx = tid + 256 * r;
            int row = idx >> 4, c4 = idx & 15;        // row = c' 0..127
            float4 m = *(const float4*)(Msum + ((size_t)b * ICH + row) * ICH + kc2 * 64 + c4 * 4);
            S1[(c4 * 4 + 0) * 133 + row] = m.x; S1[(c4 * 4 + 1) * 133 + row] = m.y;
            S1[(c4 * 4 + 2) * 133 + row] = m.z; S1[(c4 * 4 + 3) * 133 + row] = m.w;
        }
        __syncthreads();
        for (int k = 0; k < 64; ++k) {
            float av[4], bv[8];
            #pragma unroll
            for (int i = 0; i < 4; ++i) av[i] = S2[k * 65 + ty + 16 * i];
            #pragma unroll
            for (int j = 0; j < 8; ++j) bv[j] = S1[k * 133 + tx + 16 * j];
            #pragma unroll
            for (int i = 0; i < 4; ++i)
                #pragma unroll
                for (int j = 0; j < 8; ++j) acc[i][j] += av[i] * bv[j];
        }
        __syncthreads();
    }
    // KbL (scaled) into S1, stride 133: [co][c']
    #pragma unroll
    for (int i = 0; i < 4; ++i)
        #pragma unroll
        for (int j = 0; j < 8; ++j)
            S1[(ty + 16 * i) * 133 + tx + 16 * j] = acc[i][j] * INV_S;
    __syncthreads();

    // q for this tile's 64 channels
    if (tid < 64) {
        float s = w_b[cob + tid];
        #pragma unroll 8
        for (int c = 0; c < ICH; ++c) s += S1[tid * 133 + c] * theta_b[c];
        q[b * CC + cob + tid] = s;
    }

    // ---- phase B: P tile ----
    for (int cib = 0; cib < 4; ++cib) {
        float acc2[4][4];
        #pragma unroll
        for (int i = 0; i < 4; ++i)
            #pragma unroll
            for (int j = 0; j < 4; ++j) acc2[i][j] = 0.f;
        for (int kk2 = 0; kk2 < 2; ++kk2) {
            #pragma unroll
            for (int r = 0; r < 4; ++r) {             // theta_w chunk -> S2 [c'][ci]
                int idx = tid + 256 * r;
                int row = idx >> 4, c4 = idx & 15;    // row = c' local
                float4 v = *(const float4*)(theta_w + (size_t)(kk2 * 64 + row) * CC + cib * 64 + c4 * 4);
                S2[row * 65 + c4 * 4 + 0] = v.x; S2[row * 65 + c4 * 4 + 1] = v.y;
                S2[row * 65 + c4 * 4 + 2] = v.z; S2[row * 65 + c4 * 4 + 3] = v.w;
            }
            __syncthreads();
            for (int k = 0; k < 64; ++k) {
                float av[4], bv[4];
                #pragma unroll
                for (int i = 0; i < 4; ++i) av[i] = S1[(ty + 16 * i) * 133 + kk2 * 64 + k];
                #pragma unroll
                for (int j = 0; j < 4; ++j) bv[j] = S2[k * 65 + tx + 16 * j];
                #pragma unroll
                for (int i = 0; i < 4; ++i)
                    #pragma unroll
                    for (int j = 0; j < 4; ++j) acc2[i][j] += av[i] * bv[j];
            }
            __syncthreads();
        }
        #pragma unroll
        for (int i = 0; i < 4; ++i)
            #pragma unroll
            for (int j = 0; j < 4; ++j)
                P[((size_t)b * CC + cob + ty + 16 * i) * CC + cib * 64 + tx + 16 * j] =
                    __float2bfloat16(acc2[i][j]);
    }
}

// ---------------------------------------------------------------------------
// k4: m97-style MFMA  wy = P @ xt^T + q.  NO atomics: BN partial sums go to
// pbuf[c][b*32+tile] via LDS staging.  Out staging padded to stride 132.
// grid (32 t-tiles, 2 m-tiles, 8 b), block 256
// ---------------------------------------------------------------------------
__global__ __launch_bounds__(256) void k4_mfma(
    const __hip_bfloat16* __restrict__ P, const __hip_bfloat16* __restrict__ xt,
    const float* __restrict__ q, __hip_bfloat16* __restrict__ wy,
    float* __restrict__ pbuf)     // [2][256][256]: s1 then s2
{
    __shared__ short lds[128 * 132];
    __shared__ float pst1[4 * 64], pst2[4 * 64];
    short* As = lds;
    short* Bs = lds + 128 * 64;

    const int b  = blockIdx.z;
    const int m0 = blockIdx.y * 128;
    const int t0 = blockIdx.x * 128;
    const int tid = threadIdx.x;
    const int w = tid >> 6, l = tid & 63;
    const int quad = l >> 4, lm = l & 15;
    const int wm = (w & 1) * 64, wn = (w >> 1) * 64;
    const int rs = l >> 3, cs = (l & 7) * 8;

    const __hip_bfloat16* Ap = P + ((size_t)b * CC + m0) * CC;
    const __hip_bfloat16* Bp = xt + ((size_t)b * TT + t0) * CC;

    floatx4 acc[4][4];
    #pragma unroll
    for (int i = 0; i < 4; ++i)
        #pragma unroll
        for (int j = 0; j < 4; ++j) acc[i][j] = (floatx4)0.f;

    for (int kc = 0; kc < 4; ++kc) {
        const int k0 = kc * 64;
        const int rbase = w * 32;
        #pragma unroll
        for (int t = 0; t < 4; ++t) {
            gl_lds16(Ap + (size_t)(rbase + t * 8 + rs) * CC + k0 + cs, &As[(rbase + t * 8) * 64]);
            gl_lds16(Bp + (size_t)(rbase + t * 8 + rs) * CC + k0 + cs, &Bs[(rbase + t * 8) * 64]);
        }
        __syncthreads();
        #pragma unroll
        for (int ks = 0; ks < 2; ++ks) {
            short8 a[4], bb[4];
            #pragma unroll
            for (int i = 0; i < 4; ++i)
                a[i] = *(const short8*)&As[(wm + i * 16 + lm) * 64 + ks * 32 + quad * 8];
            #pragma unroll
            for (int j = 0; j < 4; ++j)
                bb[j] = *(const short8*)&Bs[(wn + j * 16 + lm) * 64 + ks * 32 + quad * 8];
            #pragma unroll
            for (int i = 0; i < 4; ++i)
                #pragma unroll
                for (int j = 0; j < 4; ++j)
                    acc[i][j] = __builtin_amdgcn_mfma_f32_16x16x32_bf16(a[i], bb[j], acc[i][j], 0, 0, 0);
        }
        __syncthreads();
    }

    // epilogue A: per-wave BN partial sums -> LDS pst (no atomics)
    #pragma unroll
    for (int i = 0; i < 4; ++i) {
        #pragma unroll
        for (int r = 0; r < 4; ++r) {
            int m = wm + i * 16 + quad * 4 + r;
            float bias = q[b * CC + m0 + m];
            float s1 = 0.f, s2 = 0.f;
            #pragma unroll
            for (int j = 0; j < 4; ++j) {
                float v = acc[i][j][r] + bias;
                s1 += v; s2 += v * v;
            }
            #pragma unroll
            for (int off = 1; off < 16; off <<= 1) {
                s1 += __shfl_xor(s1, off);
                s2 += __shfl_xor(s2, off);
            }
            if (lm == 0) {
                pst1[w * 64 + i * 16 + quad * 4 + r] = s1;
                pst2[w * 64 + i * 16 + quad * 4 + r] = s2;
            }
        }
    }

    // epilogue B: +q bias, LDS-stage bf16 tile (stride 132), wide stores
    __hip_bfloat16* Out = (__hip_bfloat16*)lds;
    #pragma unroll
    for (int i = 0; i < 4; ++i) {
        #pragma unroll
        for (int r = 0; r < 4; ++r) {
            int m = wm + i * 16 + quad * 4 + r;
            float bias = q[b * CC + m0 + m];
            #pragma unroll
            for (int j = 0; j < 4; ++j)
                Out[m * 132 + wn + j * 16 + lm] = __float2bfloat16(acc[i][j][r] + bias);
        }
    }
    __syncthreads();

    // combine the two n-half waves' partials, write pbuf (128 ch per block)
    if (tid < 128) {
        int half = tid >> 6, k = tid & 63;
        float s1 = pst1[half * 64 + k] + pst1[(2 + half) * 64 + k];
        float s2 = pst2[half * 64 + k] + pst2[(2 + half) * 64 + k];
        size_t col = (size_t)b * 32 + blockIdx.x;
        pbuf[(size_t)(m0 + tid) * 256 + col] = s1;
        pbuf[65536 + (size_t)(m0 + tid) * 256 + col] = s2;
    }

    #pragma unroll
    for (int it = 0; it < 8; ++it) {
        int idx = tid + 256 * it;
        int row = idx >> 4, cg = idx & 15;
        *(short8*)(wy + ((size_t)b * CC + m0 + row) * TT + t0 + cg * 8) =
            *(const short8*)&Out[row * 132 + cg * 8];
    }
}

// ---------------------------------------------------------------------------
// k5: reduce pbuf (256 partials/channel) -> BN coefficients. grid(256)
// ---------------------------------------------------------------------------
__global__ __launch_bounds__(256) void k5_bn(
    const float* __restrict__ pbuf, const float* __restrict__ gamma,
    const float* __restrict__ beta, float* __restrict__ coef)
{
    const int c = blockIdx.x, tid = threadIdx.x;
    float v1 = pbuf[(size_t)c * 256 + tid];
    float v2 = pbuf[65536 + (size_t)c * 256 + tid];
    #pragma unroll
    for (int off = 1; off < 64; off <<= 1) {
        v1 += __shfl_xor(v1, off);
        v2 += __shfl_xor(v2, off);
    }
    __shared__ float r1[4], r2[4];
    if ((tid & 63) == 0) { r1[tid >> 6] = v1; r2[tid >> 6] = v2; }
    __syncthreads();
    if (tid == 0) {
        float t1 = r1[0] + r1[1] + r1[2] + r1[3];
        float t2 = r2[0] + r2[1] + r2[2] + r2[3];
        float mean = t1 * INV_BT;
        float var  = t2 * INV_BT - mean * mean;
        float A = gamma[c] * rsqrtf(var + BN_EPS);
        coef[c] = A;
        coef[CC + c] = beta[c] - mean * A;
    }
}

// ---------------------------------------------------------------------------
// k6: out[b][c][t] = wy*A[c]+B[c] + xt[b][t][c]  (residual via bf16 xt,
//     transposed through padded LDS). grid (64 t-tiles, 4 c-tiles, 8 b).
// ---------------------------------------------------------------------------
__global__ __launch_bounds__(256) void k6_out(
    const __hip_bfloat16* __restrict__ wy, const __hip_bfloat16* __restrict__ xt,
    const float* __restrict__ coef, float* __restrict__ out)
{
    __shared__ float Fs[64][68];
    const int b = blockIdx.z, cb = blockIdx.y * 64, tb = blockIdx.x * 64;
    const int tid = threadIdx.x;

    {
        const int t = tid >> 2, cseg = (tid & 3) * 16;
        const __hip_bfloat16* src = xt + ((size_t)b * TT + tb + t) * CC + cb + cseg;
        short8 v0 = *(const short8*)src;
        short8 v1 = *(const short8*)(src + 8);
        const __hip_bfloat16* p0 = (const __hip_bfloat16*)&v0;
        const __hip_bfloat16* p1 = (const __hip_bfloat16*)&v1;
        #pragma unroll
        for (int e = 0; e < 8; ++e) Fs[t][cseg + e] = __bfloat162float(p0[e]);
        #pragma unroll
        for (int e = 0; e < 8; ++e) Fs[t][cseg + 8 + e] = __bfloat162float(p1[e]);
    }
    __syncthreads();

    const int c = tid >> 2, seg = (tid & 3) * 16;
    const float A = coef[cb + c], Bc = coef[CC + cb + c];
    const __hip_bfloat16* wsrc = wy + ((size_t)b * CC + cb + c) * TT + tb + seg;
    short8 w0 = *(const short8*)wsrc;
    short8 w1 = *(const short8*)(wsrc + 8);
    const __hip_bfloat16* q0 = (const __hip_bfloat16*)&w0;
    const __hip_bfloat16* q1 = (const __hip_bfloat16*)&w1;
    float* dst = out + ((size_t)b * CC + cb + c) * TT + tb + seg;
    #pragma unroll
    for (int e = 0; e < 8; ++e)
        dst[e] = __bfloat162float(q0[e]) * A + Bc + Fs[seg + e][c];
    #pragma unroll
    for (int e = 0; e < 8; ++e)
        dst[8 + e] = __bfloat162float(q1[e]) * A + Bc + Fs[seg + 8 + e][c];
}

extern "C" void kernel_launch(void* const* d_in, const int* in_sizes, int n_in,
                              void* d_out, int out_size, void* d_ws, size_t ws_size,
                              hipStream_t stream)
{
    const float* x        = (const float*)d_in[0];
    const float* theta_w  = (const float*)d_in[1];
    const float* theta_b  = (const float*)d_in[2];
    const float* phi_w    = (const float*)d_in[3];
    const float* phi_b    = (const float*)d_in[4];
    const float* g_w      = (const float*)d_in[5];
    const float* g_b      = (const float*)d_in[6];
    const float* w_w      = (const float*)d_in[7];
    const float* w_b      = (const float*)d_in[8];
    const float* bn_gamma = (const float*)d_in[9];
    const float* bn_beta  = (const float*)d_in[10];
    float* out = (float*)d_out;

    char* p = (char*)d_ws;
    __hip_bfloat16* xt    = (__hip_bfloat16*)p; p += (size_t)8388608 * 2;   // [8][4096][256]
    __hip_bfloat16* Wf    = (__hip_bfloat16*)p; p += (size_t)65536 * 2;     // [256][256]
    __hip_bfloat16* phi_g = (__hip_bfloat16*)p; p += (size_t)4194304 * 2;   // [8][256][2048]
    __hip_bfloat16* P     = (__hip_bfloat16*)p; p += (size_t)524288 * 2;    // [8][256][256]
    float* Mpart = (float*)p; p += (size_t)2097152 * 4;                     // [8][16][128][128]
    float* Msum  = (float*)p; p += (size_t)131072 * 4;                      // [8][128][128]
    float* q     = (float*)p; p += (size_t)2048 * 4;                        // [8][256]
    __hip_bfloat16* wy = (__hip_bfloat16*)p; p += (size_t)8388608 * 2;      // [8][256][4096]
    float* pbuf  = (float*)p; p += (size_t)131072 * 4;                      // [2][256][256]
    float* coef  = (float*)p;                                               // [2][256]

    k0x_transpose<<<dim3(64, 4, 9), 256, 0, stream>>>(x, xt, phi_w, g_w, Wf);
    k1_mfma<<<dim3(32, 2, 8), 256, 0, stream>>>(Wf, phi_b, g_b, xt, phi_g);
    k2_mfma<<<dim3(16, 8), 256, 0, stream>>>(phi_g, Mpart);
    k2b_reduce<<<dim3(16, 8), 256, 0, stream>>>(Mpart, Msum);
    k3_fused<<<dim3(4, 8), 256, 0, stream>>>(w_w, Msum, theta_w, theta_b, w_b, P, q);
    k4_mfma<<<dim3(32, 2, 8), 256, 0, stream>>>(P, xt, q, wy, pbuf);
    k5_bn<<<dim3(256), 256, 0, stream>>>(pbuf, bn_gamma, bn_beta, coef);
    k6_out<<<dim3(64, 4, 8), 256, 0, stream>>>(wy, xt, coef, out);
}

// Round 9
// 180.342 us; speedup vs baseline: 1.0864x; 1.0864x over previous
//
#include <hip/hip_runtime.h>
#include <hip/hip_bf16.h>

typedef __attribute__((ext_vector_type(8))) short short8;
typedef __attribute__((ext_vector_type(4))) short short4v;
typedef __attribute__((ext_vector_type(4))) float floatx4;
typedef unsigned int u32;

#define BB 8
#define CC 256
#define ICH 128
#define TT 4096
#define SS 2048
static constexpr float BN_EPS = 1e-5f;
static constexpr float INV_S  = 1.0f / 2048.0f;
static constexpr float INV_BT = 1.0f / 32768.0f;   // 1/(B*T)

// async global->LDS DMA, 16 B per lane; LDS dest = wave-uniform base + lane*16
typedef const __attribute__((address_space(1))) u32* gas_ptr;
typedef __attribute__((address_space(3))) u32* las_ptr;
__device__ __forceinline__ void gl_lds16(const void* g, void* l) {
    __builtin_amdgcn_global_load_lds((gas_ptr)g, (las_ptr)l, 16, 0, 0);
}

// ---------------------------------------------------------------------------
// k0x: transpose + convert  x[b][c][t] (f32) -> xt[b][t][c] (bf16).
// z==8 slice (y==0) additionally converts phi_w|g_w -> bf16 Wf (fused k0w).
// grid (64 t-tiles, 4 c-tiles, 9), block 256
// ---------------------------------------------------------------------------
__global__ __launch_bounds__(256) void k0x_transpose(
    const float* __restrict__ x, __hip_bfloat16* __restrict__ xt,
    const float* __restrict__ phi_w, const float* __restrict__ g_w,
    __hip_bfloat16* __restrict__ Wf)
{
    if (blockIdx.z == 8) {                      // fused weight conversion
        if (blockIdx.y != 0) return;
        int idx = blockIdx.x * 256 + threadIdx.x;   // 0..16383, 4 floats each
        const float* src = (idx < 8192) ? (phi_w + (size_t)idx * 4)
                                        : (g_w + (size_t)(idx - 8192) * 4);
        float4 v = *(const float4*)src;
        alignas(8) __hip_bfloat16 t[4];
        t[0] = __float2bfloat16(v.x); t[1] = __float2bfloat16(v.y);
        t[2] = __float2bfloat16(v.z); t[3] = __float2bfloat16(v.w);
        *(short4v*)(Wf + (size_t)idx * 4) = *(const short4v*)t;
        return;
    }

    __shared__ float Tl[64][65];
    const int b = blockIdx.z, cb = blockIdx.y * 64, tb = blockIdx.x * 64;
    const int tid = threadIdx.x;
    #pragma unroll
    for (int it = 0; it < 4; ++it) {
        int idx = tid + 256 * it;
        int row = idx >> 4, c4 = idx & 15;
        float4 v = *(const float4*)(x + ((size_t)b * CC + cb + row) * TT + tb + c4 * 4);
        Tl[row][c4 * 4 + 0] = v.x; Tl[row][c4 * 4 + 1] = v.y;
        Tl[row][c4 * 4 + 2] = v.z; Tl[row][c4 * 4 + 3] = v.w;
    }
    __syncthreads();
    #pragma unroll
    for (int it = 0; it < 2; ++it) {
        int idx = tid + 256 * it;
        int trow = idx >> 3, ch = idx & 7;
        alignas(16) __hip_bfloat16 tmp[8];
        #pragma unroll
        for (int e = 0; e < 8; ++e) tmp[e] = __float2bfloat16(Tl[ch * 8 + e][trow]);
        *(short8*)(xt + ((size_t)b * TT + tb + trow) * CC + cb + ch * 8) = *(const short8*)tmp;
    }
}

// ---------------------------------------------------------------------------
// k1: m97-style MFMA conv1x1 (stacked phi|g) + maxpool2 epilogue.
// grid (32 pre-pool t-tiles of 128, 2 m-tiles, 8 b), block 256 (4 waves)
// ---------------------------------------------------------------------------
__global__ __launch_bounds__(256) void k1_mfma(
    const __hip_bfloat16* __restrict__ Wf, const float* __restrict__ phi_b,
    const float* __restrict__ g_b, const __hip_bfloat16* __restrict__ xt,
    __hip_bfloat16* __restrict__ phi_g)
{
    __shared__ short lds[128 * 132];      // staging (32 KB) / Out (33 KB), reused
    short* As = lds;
    short* Bs = lds + 128 * 64;

    const int b  = blockIdx.z;
    const int m0 = blockIdx.y * 128;
    const int tb = blockIdx.x * 128;      // pre-pool t base
    const int s0 = blockIdx.x * 64;       // pooled output base
    const int tid = threadIdx.x;
    const int w = tid >> 6, l = tid & 63;
    const int quad = l >> 4, lm = l & 15;
    const int wm = (w & 1) * 64, wn = (w >> 1) * 64;
    const int rs = l >> 3, cs = (l & 7) * 8;   // staging row-sub / col

    const __hip_bfloat16* Ap = Wf + (size_t)m0 * CC;
    const __hip_bfloat16* Bp = xt + ((size_t)b * TT + tb) * CC;

    floatx4 acc[4][4];
    #pragma unroll
    for (int i = 0; i < 4; ++i)
        #pragma unroll
        for (int j = 0; j < 4; ++j) acc[i][j] = (floatx4)0.f;

    for (int kc = 0; kc < 4; ++kc) {
        const int k0 = kc * 64;
        const int rbase = w * 32;
        #pragma unroll
        for (int t = 0; t < 4; ++t) {
            gl_lds16(Ap + (size_t)(rbase + t * 8 + rs) * CC + k0 + cs, &As[(rbase + t * 8) * 64]);
            gl_lds16(Bp + (size_t)(rbase + t * 8 + rs) * CC + k0 + cs, &Bs[(rbase + t * 8) * 64]);
        }
        __syncthreads();
        #pragma unroll
        for (int ks = 0; ks < 2; ++ks) {
            short8 a[4], bb[4];
            #pragma unroll
            for (int i = 0; i < 4; ++i)
                a[i] = *(const short8*)&As[(wm + i * 16 + lm) * 64 + ks * 32 + quad * 8];
            #pragma unroll
            for (int j = 0; j < 4; ++j)
                bb[j] = *(const short8*)&Bs[(wn + j * 16 + lm) * 64 + ks * 32 + quad * 8];
            #pragma unroll
            for (int i = 0; i < 4; ++i)
                #pragma unroll
                for (int j = 0; j < 4; ++j)
                    acc[i][j] = __builtin_amdgcn_mfma_f32_16x16x32_bf16(a[i], bb[j], acc[i][j], 0, 0, 0);
        }
        __syncthreads();
    }

    // epilogue: stage pre-pool bf16 tile (stride 132), then pool + bias, wide stores
    __hip_bfloat16* Out = (__hip_bfloat16*)lds;
    #pragma unroll
    for (int i = 0; i < 4; ++i)
        #pragma unroll
        for (int j = 0; j < 4; ++j)
            #pragma unroll
            for (int r = 0; r < 4; ++r)
                Out[(wm + i * 16 + quad * 4 + r) * 132 + wn + j * 16 + lm] =
                    __float2bfloat16(acc[i][j][r]);
    __syncthreads();
    #pragma unroll
    for (int it = 0; it < 4; ++it) {
        int idx = tid + 256 * it;
        int orow = idx >> 3, grp = idx & 7;
        int o = m0 + orow;
        float bias = (o < ICH) ? phi_b[o] : g_b[o - ICH];
        short8 v0 = *(const short8*)&Out[orow * 132 + grp * 16];
        short8 v1 = *(const short8*)&Out[orow * 132 + grp * 16 + 8];
        const __hip_bfloat16* p0 = (const __hip_bfloat16*)&v0;
        const __hip_bfloat16* p1 = (const __hip_bfloat16*)&v1;
        alignas(16) __hip_bfloat16 o8[8];
        #pragma unroll
        for (int e = 0; e < 4; ++e)
            o8[e] = __float2bfloat16(
                fmaxf(__bfloat162float(p0[2 * e]), __bfloat162float(p0[2 * e + 1])) + bias);
        #pragma unroll
        for (int e = 0; e < 4; ++e)
            o8[4 + e] = __float2bfloat16(
                fmaxf(__bfloat162float(p1[2 * e]), __bfloat162float(p1[2 * e + 1])) + bias);
        *(short8*)(phi_g + ((size_t)b * CC + o) * SS + s0 + grp * 8) = *(const short8*)o8;
    }
}

// ---------------------------------------------------------------------------
// k2: MFMA Gram partials over 512-wide s-chunks (phi_g read exactly once):
//   Mpart[b][sc][c'][c] = sum_{s in 512-chunk sc} phi[c'][s] * g[c][s]
// grid (4 sc, 8 b), block 256, K-loop of 8 BK=64 tiles. k2b is gone.
// ---------------------------------------------------------------------------
__global__ __launch_bounds__(256) void k2_mfma(
    const __hip_bfloat16* __restrict__ phi_g, float* __restrict__ Mpart)
{
    __shared__ short lds[2 * 128 * 64];
    short* As = lds;
    short* Bs = lds + 128 * 64;
    const int sc = blockIdx.x, b = blockIdx.y;
    const int tid = threadIdx.x;
    const int w = tid >> 6, l = tid & 63;
    const int quad = l >> 4, lm = l & 15;
    const int wm = (w & 1) * 64, wn = (w >> 1) * 64;
    const int rs = l >> 3, cs = (l & 7) * 8;

    const __hip_bfloat16* Ap = phi_g + (size_t)b * CC * SS + sc * 512;   // phi rows
    const __hip_bfloat16* Bp = Ap + (size_t)ICH * SS;                     // g rows

    floatx4 acc[4][4];
    #pragma unroll
    for (int i = 0; i < 4; ++i)
        #pragma unroll
        for (int j = 0; j < 4; ++j) acc[i][j] = (floatx4)0.f;

    for (int kc = 0; kc < 8; ++kc) {
        const int k0 = kc * 64;
        const int rbase = w * 32;
        #pragma unroll
        for (int t = 0; t < 4; ++t) {
            gl_lds16(Ap + (size_t)(rbase + t * 8 + rs) * SS + k0 + cs, &As[(rbase + t * 8) * 64]);
            gl_lds16(Bp + (size_t)(rbase + t * 8 + rs) * SS + k0 + cs, &Bs[(rbase + t * 8) * 64]);
        }
        __syncthreads();
        #pragma unroll
        for (int ks = 0; ks < 2; ++ks) {
            short8 a[4], bb[4];
            #pragma unroll
            for (int i = 0; i < 4; ++i)
                a[i] = *(const short8*)&As[(wm + i * 16 + lm) * 64 + ks * 32 + quad * 8];
            #pragma unroll
            for (int j = 0; j < 4; ++j)
                bb[j] = *(const short8*)&Bs[(wn + j * 16 + lm) * 64 + ks * 32 + quad * 8];
            #pragma unroll
            for (int i = 0; i < 4; ++i)
                #pragma unroll
                for (int j = 0; j < 4; ++j)
                    acc[i][j] = __builtin_amdgcn_mfma_f32_16x16x32_bf16(a[i], bb[j], acc[i][j], 0, 0, 0);
        }
        __syncthreads();
    }

    float* dst = Mpart + ((size_t)(b * 4 + sc)) * ICH * ICH;
    #pragma unroll
    for (int i = 0; i < 4; ++i)
        #pragma unroll
        for (int j = 0; j < 4; ++j)
            #pragma unroll
            for (int r = 0; r < 4; ++r)
                dst[(size_t)(wm + i * 16 + quad * 4 + r) * ICH + wn + j * 16 + lm] = acc[i][j][r];
}

// ---------------------------------------------------------------------------
// k3a: Kb[b][co][c'] = (1/S) * sum_c w_w[co][c] * M[b][c'][c]
//      (M = inline sum of 4 partials; 2.1 MB Mpart is L2-hot)
// grid (2 c'-tiles, 4 co-tiles, 8 b) = 64 blocks
// ---------------------------------------------------------------------------
__global__ __launch_bounds__(256) void k3a_kb(
    const float* __restrict__ w_w, const float* __restrict__ Mpart,
    float* __restrict__ Kb)
{
    __shared__ float Al[64][65];
    __shared__ float Bl[64][65];
    const int b = blockIdx.z;
    const int cob = blockIdx.y * 64;
    const int cpb = blockIdx.x * 64;
    const int tid = threadIdx.x;
    const int tx = tid & 15, ty = tid >> 4;

    float acc[4][4] = {};
    for (int kc2 = 0; kc2 < 2; ++kc2) {
        #pragma unroll
        for (int r = 0; r < 4; ++r) {
            int idx = tid + 256 * r;
            int row = idx >> 4, c4 = idx & 15;
            float4 v = *(const float4*)(w_w + (size_t)(cob + row) * ICH + kc2 * 64 + c4 * 4);
            Al[c4 * 4 + 0][row] = v.x; Al[c4 * 4 + 1][row] = v.y;
            Al[c4 * 4 + 2][row] = v.z; Al[c4 * 4 + 3][row] = v.w;
            float4 s = {0.f, 0.f, 0.f, 0.f};
            #pragma unroll
            for (int sc = 0; sc < 4; ++sc) {
                float4 m = *(const float4*)(Mpart + (((size_t)b * 4 + sc) * ICH + cpb + row) * ICH + kc2 * 64 + c4 * 4);
                s.x += m.x; s.y += m.y; s.z += m.z; s.w += m.w;
            }
            Bl[c4 * 4 + 0][row] = s.x; Bl[c4 * 4 + 1][row] = s.y;
            Bl[c4 * 4 + 2][row] = s.z; Bl[c4 * 4 + 3][row] = s.w;
        }
        __syncthreads();
        for (int k = 0; k < 64; ++k) {
            float av[4], bv[4];
            #pragma unroll
            for (int i = 0; i < 4; ++i) av[i] = Al[k][ty + 16 * i];
            #pragma unroll
            for (int j = 0; j < 4; ++j) bv[j] = Bl[k][tx + 16 * j];
            #pragma unroll
            for (int i = 0; i < 4; ++i)
                #pragma unroll
                for (int j = 0; j < 4; ++j) acc[i][j] += av[i] * bv[j];
        }
        __syncthreads();
    }
    #pragma unroll
    for (int i = 0; i < 4; ++i)
        #pragma unroll
        for (int j = 0; j < 4; ++j)
            Kb[((size_t)b * CC + cob + ty + 16 * i) * ICH + cpb + tx + 16 * j] = acc[i][j] * INV_S;
}

// ---------------------------------------------------------------------------
// k3b: P[b][co][ci] = sum_{c'} Kb[b][co][c'] * theta_w[c'][ci]   (bf16 output)
//      + (cib==0 blocks) q[b][co] = w_b[co] + Kb[b][co] . theta_b
// grid (2 ci-tiles of 128, 4 co-tiles, 8 b) = 64 blocks
// ---------------------------------------------------------------------------
__global__ __launch_bounds__(256) void k3b_p(
    const float* __restrict__ Kb, const float* __restrict__ theta_w,
    const float* __restrict__ theta_b, const float* __restrict__ w_b,
    __hip_bfloat16* __restrict__ P, float* __restrict__ q)
{
    __shared__ float Al[64][65];
    __shared__ float Bl[64][128];
    const int b = blockIdx.z;
    const int cob = blockIdx.y * 64;
    const int cib = blockIdx.x * 128;
    const int tid = threadIdx.x;
    const int tx = tid & 15, ty = tid >> 4;

    float acc[4][8] = {};
    for (int kc2 = 0; kc2 < 2; ++kc2) {
        #pragma unroll
        for (int r = 0; r < 4; ++r) {
            int idx = tid + 256 * r;
            int row = idx >> 4, c4 = idx & 15;
            float4 v = *(const float4*)(Kb + ((size_t)b * CC + cob + row) * ICH + kc2 * 64 + c4 * 4);
            Al[c4 * 4 + 0][row] = v.x; Al[c4 * 4 + 1][row] = v.y;
            Al[c4 * 4 + 2][row] = v.z; Al[c4 * 4 + 3][row] = v.w;
        }
        #pragma unroll
        for (int r = 0; r < 8; ++r) {
            int idx = tid + 256 * r;
            int row = idx >> 5, c4 = idx & 31;
            *(float4*)(&Bl[row][c4 * 4]) =
                *(const float4*)(theta_w + (size_t)(kc2 * 64 + row) * CC + cib + c4 * 4);
        }
        __syncthreads();
        for (int k = 0; k < 64; ++k) {
            float av[4], bv[8];
            #pragma unroll
            for (int i = 0; i < 4; ++i) av[i] = Al[k][ty + 16 * i];
            #pragma unroll
            for (int j = 0; j < 8; ++j) bv[j] = Bl[k][tx + 16 * j];
            #pragma unroll
            for (int i = 0; i < 4; ++i)
                #pragma unroll
                for (int j = 0; j < 8; ++j) acc[i][j] += av[i] * bv[j];
        }
        __syncthreads();
    }
    #pragma unroll
    for (int i = 0; i < 4; ++i)
        #pragma unroll
        for (int j = 0; j < 8; ++j)
            P[((size_t)b * CC + cob + ty + 16 * i) * CC + cib + tx + 16 * j] =
                __float2bfloat16(acc[i][j]);

    // fused k3c: q for this block's 64 output channels (one block-column only)
    if (blockIdx.x == 0 && tid < 64) {
        const float* kr = Kb + ((size_t)b * CC + cob + tid) * ICH;
        float s = w_b[cob + tid];
        #pragma unroll 8
        for (int c = 0; c < ICH; ++c) s += kr[c] * theta_b[c];
        q[b * CC + cob + tid] = s;
    }
}

// ---------------------------------------------------------------------------
// k4: m97-style MFMA  wy = P @ xt^T + q.  NO atomics: BN partial sums go to
// pbuf[c][b*32+tile] via LDS staging.  Out staging padded to stride 132.
// grid (32 t-tiles, 2 m-tiles, 8 b), block 256
// ---------------------------------------------------------------------------
__global__ __launch_bounds__(256) void k4_mfma(
    const __hip_bfloat16* __restrict__ P, const __hip_bfloat16* __restrict__ xt,
    const float* __restrict__ q, __hip_bfloat16* __restrict__ wy,
    float* __restrict__ pbuf)     // [2][256][256]: s1 then s2
{
    __shared__ short lds[128 * 132];
    __shared__ float pst1[4 * 64], pst2[4 * 64];
    short* As = lds;
    short* Bs = lds + 128 * 64;

    const int b  = blockIdx.z;
    const int m0 = blockIdx.y * 128;
    const int t0 = blockIdx.x * 128;
    const int tid = threadIdx.x;
    const int w = tid >> 6, l = tid & 63;
    const int quad = l >> 4, lm = l & 15;
    const int wm = (w & 1) * 64, wn = (w >> 1) * 64;
    const int rs = l >> 3, cs = (l & 7) * 8;

    const __hip_bfloat16* Ap = P + ((size_t)b * CC + m0) * CC;
    const __hip_bfloat16* Bp = xt + ((size_t)b * TT + t0) * CC;

    floatx4 acc[4][4];
    #pragma unroll
    for (int i = 0; i < 4; ++i)
        #pragma unroll
        for (int j = 0; j < 4; ++j) acc[i][j] = (floatx4)0.f;

    for (int kc = 0; kc < 4; ++kc) {
        const int k0 = kc * 64;
        const int rbase = w * 32;
        #pragma unroll
        for (int t = 0; t < 4; ++t) {
            gl_lds16(Ap + (size_t)(rbase + t * 8 + rs) * CC + k0 + cs, &As[(rbase + t * 8) * 64]);
            gl_lds16(Bp + (size_t)(rbase + t * 8 + rs) * CC + k0 + cs, &Bs[(rbase + t * 8) * 64]);
        }
        __syncthreads();
        #pragma unroll
        for (int ks = 0; ks < 2; ++ks) {
            short8 a[4], bb[4];
            #pragma unroll
            for (int i = 0; i < 4; ++i)
                a[i] = *(const short8*)&As[(wm + i * 16 + lm) * 64 + ks * 32 + quad * 8];
            #pragma unroll
            for (int j = 0; j < 4; ++j)
                bb[j] = *(const short8*)&Bs[(wn + j * 16 + lm) * 64 + ks * 32 + quad * 8];
            #pragma unroll
            for (int i = 0; i < 4; ++i)
                #pragma unroll
                for (int j = 0; j < 4; ++j)
                    acc[i][j] = __builtin_amdgcn_mfma_f32_16x16x32_bf16(a[i], bb[j], acc[i][j], 0, 0, 0);
        }
        __syncthreads();
    }

    // epilogue A: per-wave BN partial sums -> LDS pst (no atomics)
    #pragma unroll
    for (int i = 0; i < 4; ++i) {
        #pragma unroll
        for (int r = 0; r < 4; ++r) {
            int m = wm + i * 16 + quad * 4 + r;
            float bias = q[b * CC + m0 + m];
            float s1 = 0.f, s2 = 0.f;
            #pragma unroll
            for (int j = 0; j < 4; ++j) {
                float v = acc[i][j][r] + bias;
                s1 += v; s2 += v * v;
            }
            #pragma unroll
            for (int off = 1; off < 16; off <<= 1) {
                s1 += __shfl_xor(s1, off);
                s2 += __shfl_xor(s2, off);
            }
            if (lm == 0) {
                pst1[w * 64 + i * 16 + quad * 4 + r] = s1;
                pst2[w * 64 + i * 16 + quad * 4 + r] = s2;
            }
        }
    }

    // epilogue B: +q bias, LDS-stage bf16 tile (stride 132), wide stores
    __hip_bfloat16* Out = (__hip_bfloat16*)lds;
    #pragma unroll
    for (int i = 0; i < 4; ++i) {
        #pragma unroll
        for (int r = 0; r < 4; ++r) {
            int m = wm + i * 16 + quad * 4 + r;
            float bias = q[b * CC + m0 + m];
            #pragma unroll
            for (int j = 0; j < 4; ++j)
                Out[m * 132 + wn + j * 16 + lm] = __float2bfloat16(acc[i][j][r] + bias);
        }
    }
    __syncthreads();

    // combine the two n-half waves' partials, write pbuf (128 ch per block)
    if (tid < 128) {
        int half = tid >> 6, k = tid & 63;
        float s1 = pst1[half * 64 + k] + pst1[(2 + half) * 64 + k];
        float s2 = pst2[half * 64 + k] + pst2[(2 + half) * 64 + k];
        size_t col = (size_t)b * 32 + blockIdx.x;
        pbuf[(size_t)(m0 + tid) * 256 + col] = s1;
        pbuf[65536 + (size_t)(m0 + tid) * 256 + col] = s2;
    }

    #pragma unroll
    for (int it = 0; it < 8; ++it) {
        int idx = tid + 256 * it;
        int row = idx >> 4, cg = idx & 15;
        *(short8*)(wy + ((size_t)b * CC + m0 + row) * TT + t0 + cg * 8) =
            *(const short8*)&Out[row * 132 + cg * 8];
    }
}

// ---------------------------------------------------------------------------
// k5: reduce pbuf (256 partials/channel) -> BN coefficients. grid(256)
// ---------------------------------------------------------------------------
__global__ __launch_bounds__(256) void k5_bn(
    const float* __restrict__ pbuf, const float* __restrict__ gamma,
    const float* __restrict__ beta, float* __restrict__ coef)
{
    const int c = blockIdx.x, tid = threadIdx.x;
    float v1 = pbuf[(size_t)c * 256 + tid];
    float v2 = pbuf[65536 + (size_t)c * 256 + tid];
    #pragma unroll
    for (int off = 1; off < 64; off <<= 1) {
        v1 += __shfl_xor(v1, off);
        v2 += __shfl_xor(v2, off);
    }
    __shared__ float r1[4], r2[4];
    if ((tid & 63) == 0) { r1[tid >> 6] = v1; r2[tid >> 6] = v2; }
    __syncthreads();
    if (tid == 0) {
        float t1 = r1[0] + r1[1] + r1[2] + r1[3];
        float t2 = r2[0] + r2[1] + r2[2] + r2[3];
        float mean = t1 * INV_BT;
        float var  = t2 * INV_BT - mean * mean;
        float A = gamma[c] * rsqrtf(var + BN_EPS);
        coef[c] = A;
        coef[CC + c] = beta[c] - mean * A;
    }
}

// ---------------------------------------------------------------------------
// k6: out[b][c][t] = wy*A[c]+B[c] + xt[b][t][c]  (residual via bf16 xt,
//     transposed through padded LDS). grid (64 t-tiles, 4 c-tiles, 8 b).
// ---------------------------------------------------------------------------
__global__ __launch_bounds__(256) void k6_out(
    const __hip_bfloat16* __restrict__ wy, const __hip_bfloat16* __restrict__ xt,
    const float* __restrict__ coef, float* __restrict__ out)
{
    __shared__ float Fs[64][68];
    const int b = blockIdx.z, cb = blockIdx.y * 64, tb = blockIdx.x * 64;
    const int tid = threadIdx.x;

    {
        const int t = tid >> 2, cseg = (tid & 3) * 16;
        const __hip_bfloat16* src = xt + ((size_t)b * TT + tb + t) * CC + cb + cseg;
        short8 v0 = *(const short8*)src;
        short8 v1 = *(const short8*)(src + 8);
        const __hip_bfloat16* p0 = (const __hip_bfloat16*)&v0;
        const __hip_bfloat16* p1 = (const __hip_bfloat16*)&v1;
        #pragma unroll
        for (int e = 0; e < 8; ++e) Fs[t][cseg + e] = __bfloat162float(p0[e]);
        #pragma unroll
        for (int e = 0; e < 8; ++e) Fs[t][cseg + 8 + e] = __bfloat162float(p1[e]);
    }
    __syncthreads();

    const int c = tid >> 2, seg = (tid & 3) * 16;
    const float A = coef[cb + c], Bc = coef[CC + cb + c];
    const __hip_bfloat16* wsrc = wy + ((size_t)b * CC + cb + c) * TT + tb + seg;
    short8 w0 = *(const short8*)wsrc;
    short8 w1 = *(const short8*)(wsrc + 8);
    const __hip_bfloat16* q0 = (const __hip_bfloat16*)&w0;
    const __hip_bfloat16* q1 = (const __hip_bfloat16*)&w1;
    float* dst = out + ((size_t)b * CC + cb + c) * TT + tb + seg;
    #pragma unroll
    for (int e = 0; e < 8; ++e)
        dst[e] = __bfloat162float(q0[e]) * A + Bc + Fs[seg + e][c];
    #pragma unroll
    for (int e = 0; e < 8; ++e)
        dst[8 + e] = __bfloat162float(q1[e]) * A + Bc + Fs[seg + 8 + e][c];
}

extern "C" void kernel_launch(void* const* d_in, const int* in_sizes, int n_in,
                              void* d_out, int out_size, void* d_ws, size_t ws_size,
                              hipStream_t stream)
{
    const float* x        = (const float*)d_in[0];
    const float* theta_w  = (const float*)d_in[1];
    const float* theta_b  = (const float*)d_in[2];
    const float* phi_w    = (const float*)d_in[3];
    const float* phi_b    = (const float*)d_in[4];
    const float* g_w      = (const float*)d_in[5];
    const float* g_b      = (const float*)d_in[6];
    const float* w_w      = (const float*)d_in[7];
    const float* w_b      = (const float*)d_in[8];
    const float* bn_gamma = (const float*)d_in[9];
    const float* bn_beta  = (const float*)d_in[10];
    float* out = (float*)d_out;

    char* p = (char*)d_ws;
    __hip_bfloat16* xt    = (__hip_bfloat16*)p; p += (size_t)8388608 * 2;   // [8][4096][256]
    __hip_bfloat16* Wf    = (__hip_bfloat16*)p; p += (size_t)65536 * 2;     // [256][256]
    __hip_bfloat16* phi_g = (__hip_bfloat16*)p; p += (size_t)4194304 * 2;   // [8][256][2048]
    __hip_bfloat16* P     = (__hip_bfloat16*)p; p += (size_t)524288 * 2;    // [8][256][256]
    float* Mpart = (float*)p; p += (size_t)524288 * 4;                      // [8][4][128][128]
    float* Kb    = (float*)p; p += (size_t)262144 * 4;                      // [8][256][128]
    float* q     = (float*)p; p += (size_t)2048 * 4;                        // [8][256]
    __hip_bfloat16* wy = (__hip_bfloat16*)p; p += (size_t)8388608 * 2;      // [8][256][4096]
    float* pbuf  = (float*)p; p += (size_t)131072 * 4;                      // [2][256][256]
    float* coef  = (float*)p;                                               // [2][256]

    k0x_transpose<<<dim3(64, 4, 9), 256, 0, stream>>>(x, xt, phi_w, g_w, Wf);
    k1_mfma<<<dim3(32, 2, 8), 256, 0, stream>>>(Wf, phi_b, g_b, xt, phi_g);
    k2_mfma<<<dim3(4, 8), 256, 0, stream>>>(phi_g, Mpart);
    k3a_kb<<<dim3(2, 4, 8), 256, 0, stream>>>(w_w, Mpart, Kb);
    k3b_p<<<dim3(2, 4, 8), 256, 0, stream>>>(Kb, theta_w, theta_b, w_b, P, q);
    k4_mfma<<<dim3(32, 2, 8), 256, 0, stream>>>(P, xt, q, wy, pbuf);
    k5_bn<<<dim3(256), 256, 0, stream>>>(pbuf, bn_gamma, bn_beta, coef);
    k6_out<<<dim3(64, 4, 8), 256, 0, stream>>>(wy, xt, coef, out);
}